// Round 5
// baseline (31777.960 us; speedup 1.0000x reference)
//
#include <hip/hip_runtime.h>
#include <hip/hip_bf16.h>

typedef __attribute__((ext_vector_type(8))) short short8;
typedef __attribute__((ext_vector_type(4))) float f32x4;

#define T_STEPS 2048
#define HDIM 512
#define OUT_STRIDE (64 * 512)   // elems per time slice
#define NGROUP 8
#define NSLICE 8
#define RING_OFF 4096           // byte offset of ring inside d_ws
#define SPIN_CAP 2000000        // ~0.25 s worth of polls; 5000x a normal wait

#define MFMA16 __builtin_amdgcn_mfma_f32_16x16x32_bf16
#define ALOAD(p)   __hip_atomic_load((p), __ATOMIC_RELAXED, __HIP_MEMORY_SCOPE_AGENT)
#define AADD(p,v)  __hip_atomic_fetch_add((p), (v), __ATOMIC_RELAXED, __HIP_MEMORY_SCOPE_AGENT)
#define ASWAP(p,v) (void)__hip_atomic_exchange((p), (v), __ATOMIC_RELAXED, __HIP_MEMORY_SCOPE_AGENT)

static __device__ __forceinline__ short f2bf(float f) {
    __hip_bfloat16 h = __float2bfloat16(f);
    return __builtin_bit_cast(short, h);
}
static __device__ __forceinline__ float bf2f(short s) {
    unsigned u = ((unsigned)(unsigned short)s) << 16;
    return __builtin_bit_cast(float, u);
}
// split f32 -> bf16 hi + bf16 lo (lo = bf16(x - hi)); exact for x = +-1.0
static __device__ __forceinline__ void split8v(f32x4 u, f32x4 v, short8& hi, short8& lo) {
#pragma unroll
    for (int j = 0; j < 4; ++j) { short h = f2bf(u[j]); hi[j] = h; lo[j] = f2bf(u[j] - bf2f(h)); }
#pragma unroll
    for (int j = 0; j < 4; ++j) { short h = f2bf(v[j]); hi[4 + j] = h; lo[4 + j] = f2bf(v[j] - bf2f(h)); }
}

union S8U { short8 s8; unsigned u[4]; };

// unpack one u64 = two packed ring words {hi16|lo16<<16} (cols w, w+1)
// into a (hi0|hi1<<16) word and a (lo0|lo1<<16) word via v_perm_b32.
static __device__ __forceinline__ void unpack2(unsigned long long q, unsigned& hiw, unsigned& low) {
    unsigned p0 = (unsigned)q, p1 = (unsigned)(q >> 32);
    hiw = __builtin_amdgcn_perm(p1, p0, 0x05040100u);
    low = __builtin_amdgcn_perm(p1, p0, 0x07060302u);
}

// Persistent RNN, emulated-f32 via 3-term bf16 hi/lo MFMA.
// Grid 64 WGs = 8 batch-groups x 8 col-slices, all co-resident (64 <= 256 CUs
// at launch_bounds(256,1)).
// Cross-WG protocol (fence-free, hang-proof):
//   - ALL cross-WG writes are RMW atomics, which execute AT the device
//     coherence point (HW-guaranteed visible; the class Round 3 verified):
//     ring data = atomic_exchange (no-return swap), barrier = per-group
//     monotone counter via fetch_add (consumer at step t waits cnt >= 8t).
//   - All cross-WG reads are relaxed agent-scope atomic loads (sc1: bypass
//     and never allocate in L1/L2 -> no stale-copy hazard; proven by R3's
//     working spin).
//   - Producer order: swaps -> vmcnt(0) drain (acked at coherence point) ->
//     barrier -> tid0 fetch_add. Consumer: poll counter -> barrier -> loads.
//   - WAR on 2-slot ring: counter waits bound peer skew to <= 1 step.
//   - Bounded spin + global abort flag: a wedged protocol terminates with a
//     wrong answer instead of hanging the GPU.
__global__ __launch_bounds__(256, 1) void rnn_persistent(
    const float* __restrict__ input,   // (2048, 64, 512) f32
    const float* __restrict__ weight,  // (1024, 512) f32: Wx rows 0..511, Wh rows 512..1023
    const float* __restrict__ bias,    // (512)
    const float* __restrict__ init_h,  // (512)
    float* __restrict__ out,           // (2049, 64, 512) f32
    unsigned char* __restrict__ ws)
{
    unsigned* cnt  = (unsigned*)ws;                 // [8] counters, 64B apart (cnt[g*16])
    unsigned* abt  = (unsigned*)(ws + 1024);        // global abort flag
    unsigned* ring = (unsigned*)(ws + RING_OFF);    // [2][64][512] u32 packed {bf16hi|bf16lo<<16}

    __shared__ int sh_abort;

    const int tid  = threadIdx.x;
    const int lane = tid & 63;
    const int wv   = tid >> 6;
    const int g    = blockIdx.x & 7;    // batch group (rows 8g..8g+7)
    const int s    = blockIdx.x >> 3;   // col slice (cols 64s..64s+63)
    const int r16  = lane & 15;
    const int kg   = lane >> 4;
    const int col  = s * 64 + wv * 16 + r16;
    const int brow = g * 8 + (r16 & 7);
    const int koff = kg * 8;
    (void)wv;

    // ---- one-time: weight column slices as hi/lo bf16 B-fragments ----
    short8 whb_hi[16], whb_lo[16], wxb_hi[16], wxb_lo[16];
#pragma unroll
    for (int c = 0; c < 16; ++c) {
        short8 xh, xl, hh, hl;
#pragma unroll
        for (int j = 0; j < 8; ++j) {
            const int k = c * 32 + koff + j;
            const float wx = weight[(size_t)k * HDIM + col];
            const float wh = weight[(size_t)(HDIM + k) * HDIM + col];
            short a = f2bf(wx); xh[j] = a; xl[j] = f2bf(wx - bf2f(a));
            short b = f2bf(wh); hh[j] = b; hl[j] = f2bf(wh - bf2f(b));
        }
        wxb_hi[c] = xh; wxb_lo[c] = xl; whb_hi[c] = hh; whb_lo[c] = hl;
    }
    const float bv = bias[col];

    // ---- out[0] = broadcast init_hidden (this WG's slice) ----
    for (int idx = tid; idx < 8 * 64; idx += 256) {
        const int rr = idx >> 6, cc = idx & 63;
        out[(size_t)(g * 8 + rr) * HDIM + s * 64 + cc] = init_h[s * 64 + cc];
    }

    // ---- xp(0) = bias + input[0] @ Wx (3 hi/lo chains) ----
    f32x4 xpA = {bv, bv, bv, bv}, xpB = {0, 0, 0, 0}, xpC = {0, 0, 0, 0};
    {
        const float* ip = input + (size_t)brow * HDIM;
#pragma unroll
        for (int c = 0; c < 16; ++c) {
            const int k0 = c * 32 + koff;
            f32x4 u = *(const f32x4*)(ip + k0);
            f32x4 v = *(const f32x4*)(ip + k0 + 4);
            short8 hi, lo; split8v(u, v, hi, lo);
            xpA = MFMA16(hi, wxb_hi[c], xpA, 0, 0, 0);
            xpB = MFMA16(lo, wxb_hi[c], xpB, 0, 0, 0);
            xpC = MFMA16(hi, wxb_lo[c], xpC, 0, 0, 0);
        }
    }

    for (int t = 0; t < T_STEPS; ++t) {
        const bool has_next = (t + 1 < T_STEPS);

        // ---- wait: group counter >= 8t (all 8 slices posted h_t) ----
        if (t > 0) {
            if (tid == 0) {
                const unsigned target = 8u * (unsigned)t;
                int to = 0, it = 0;
                while (ALOAD(&cnt[g * 16]) < target) {
                    if ((++it & 2047) == 0) {
                        if (it > SPIN_CAP) { AADD(abt, 1u); to = 1; break; }
                        if (ALOAD(abt) != 0u) { to = 1; break; }
                    }
                }
                sh_abort = to;
            }
            __syncthreads();
            if (sh_abort) return;   // uniform exit: terminate instead of hang
        }

        // ---- A-fragments of h_t (hi/lo bf16) ----
        short8 ha_hi[16], ha_lo[16];
        if (t == 0) {
#pragma unroll
            for (int c = 0; c < 16; ++c) {
                const int k0 = c * 32 + koff;
                f32x4 u = *(const f32x4*)(init_h + k0);
                f32x4 v = *(const f32x4*)(init_h + k0 + 4);
                split8v(u, v, ha_hi[c], ha_lo[c]);
            }
        } else {
            const unsigned* rb = ring + (t & 1) * OUT_STRIDE + brow * HDIM;
#pragma unroll
            for (int c = 0; c < 16; ++c) {
                const unsigned* p = rb + c * 32 + koff;
                unsigned long long q0 = ALOAD((const unsigned long long*)(p + 0));
                unsigned long long q1 = ALOAD((const unsigned long long*)(p + 2));
                unsigned long long q2 = ALOAD((const unsigned long long*)(p + 4));
                unsigned long long q3 = ALOAD((const unsigned long long*)(p + 6));
                S8U hh, hl;
                unpack2(q0, hh.u[0], hl.u[0]);
                unpack2(q1, hh.u[1], hl.u[1]);
                unpack2(q2, hh.u[2], hl.u[2]);
                unpack2(q3, hh.u[3], hl.u[3]);
                ha_hi[c] = hh.s8; ha_lo[c] = hl.s8;
            }
        }

        // ---- preact = xp(t) + h_t @ Wh (3 independent chains) ----
        f32x4 aA = xpA, aB = xpB, aC = xpC;
#pragma unroll
        for (int c = 0; c < 16; ++c) {
            aA = MFMA16(ha_hi[c], whb_hi[c], aA, 0, 0, 0);
            aB = MFMA16(ha_lo[c], whb_hi[c], aB, 0, 0, 0);
            aC = MFMA16(ha_hi[c], whb_lo[c], aC, 0, 0, 0);
        }

        float hn[4];
#pragma unroll
        for (int r = 0; r < 4; ++r) hn[r] = tanhf(aA[r] + aB[r] + aC[r]);

        // ---- post h_{t+1} to ring: RMW swaps (execute at coherence point) ----
        if (kg < 2 && has_next) {
            unsigned* wsl = ring + ((t + 1) & 1) * OUT_STRIDE;
            const int rowb = g * 8 + kg * 4;
#pragma unroll
            for (int r = 0; r < 4; ++r) {
                const short hi = f2bf(hn[r]);
                const short lo = f2bf(hn[r] - bf2f(hi));
                const unsigned pk = (unsigned)(unsigned short)hi |
                                    ((unsigned)(unsigned short)lo << 16);
                ASWAP(&wsl[(size_t)(rowb + r) * HDIM + col], pk);
            }
        }
        // drain swaps (acked at coherence point), then signal via counter RMW
        asm volatile("s_waitcnt vmcnt(0)" ::: "memory");
        __syncthreads();
        if (tid == 0 && has_next)
            AADD(&cnt[g * 16], 1u);

        // ---- off critical path: out stores + xp(t+1) ----
        if (kg < 2) {
            float* op = out + (size_t)(t + 1) * OUT_STRIDE
                            + (size_t)(g * 8 + kg * 4) * HDIM + col;
#pragma unroll
            for (int r = 0; r < 4; ++r)
                __builtin_nontemporal_store(hn[r], op + r * HDIM);
        }
        if (has_next) {
            const float* ip = input + (size_t)(t + 1) * OUT_STRIDE + (size_t)brow * HDIM;
            f32x4 nA = {bv, bv, bv, bv}, nB = {0, 0, 0, 0}, nC = {0, 0, 0, 0};
#pragma unroll
            for (int c = 0; c < 16; ++c) {
                const int k0 = c * 32 + koff;
                f32x4 u = *(const f32x4*)(ip + k0);
                f32x4 v = *(const f32x4*)(ip + k0 + 4);
                short8 hi, lo; split8v(u, v, hi, lo);
                nA = MFMA16(hi, wxb_hi[c], nA, 0, 0, 0);
                nB = MFMA16(lo, wxb_hi[c], nB, 0, 0, 0);
                nC = MFMA16(hi, wxb_lo[c], nC, 0, 0, 0);
            }
            xpA = nA; xpB = nB; xpC = nC;
        }
    }
}

extern "C" void kernel_launch(void* const* d_in, const int* in_sizes, int n_in,
                              void* d_out, int out_size, void* d_ws, size_t ws_size,
                              hipStream_t stream) {
    const float* input  = (const float*)d_in[0];
    const float* weight = (const float*)d_in[1];
    const float* biasp  = (const float*)d_in[2];
    const float* inith  = (const float*)d_in[3];
    float* out = (float*)d_out;

    // re-zero counters + abort flag each call (graph-replay deterministic);
    // ring is fully rewritten before each read, no reset needed.
    hipMemsetAsync(d_ws, 0, RING_OFF, stream);

    rnn_persistent<<<dim3(NGROUP * NSLICE), dim3(256), 0, stream>>>(
        input, weight, biasp, inith, out, (unsigned char*)d_ws);
}

// Round 6
// 12016.821 us; speedup vs baseline: 2.6445x; 2.6445x over previous
//
#include <hip/hip_runtime.h>
#include <hip/hip_bf16.h>

typedef __attribute__((ext_vector_type(8))) short short8;
typedef __attribute__((ext_vector_type(4))) float f32x4;
typedef __attribute__((ext_vector_type(4))) unsigned u32x4;

#define T_STEPS 2048
#define HDIM 512
#define SLICE_T (64 * 512)      // elems per time slice
#define NGROUP 8                // batch groups (8 rows each)
#define NSLICE 16               // column slices (32 cols each)
#define CAN_OFF 0               // canaries: [128] lines, 128B apart (16KB)
#define RING_OFF 16384          // ring: [2][64][512] u32 packed (256KB)
#define SPIN_CAP 200000         // ~0.12s of polls; huge margin, hang-proof

#define MFMA16 __builtin_amdgcn_mfma_f32_16x16x32_bf16
#define ALOAD(p)   __hip_atomic_load((p), __ATOMIC_RELAXED, __HIP_MEMORY_SCOPE_AGENT)
#define ASWAP(p,v) (void)__hip_atomic_exchange((p), (v), __ATOMIC_RELAXED, __HIP_MEMORY_SCOPE_AGENT)

static __device__ __forceinline__ short f2bf(float f) {
    __hip_bfloat16 h = __float2bfloat16(f);
    return __builtin_bit_cast(short, h);
}
static __device__ __forceinline__ float bf2f(short s) {
    unsigned u = ((unsigned)(unsigned short)s) << 16;
    return __builtin_bit_cast(float, u);
}
// pack f32 -> u32 {bf16hi | bf16lo<<16}, lo = bf16(x - hi); exact for +-1.0
static __device__ __forceinline__ unsigned packsplit(float f) {
    short hi = f2bf(f);
    short lo = f2bf(f - bf2f(hi));
    return (unsigned)(unsigned short)hi | ((unsigned)(unsigned short)lo << 16);
}
// two packed words (cols j, j+1) -> bf16x2 hi-word and lo-word
static __device__ __forceinline__ void unpack2w(unsigned p0, unsigned p1,
                                                unsigned& hw, unsigned& lw) {
    hw = __builtin_amdgcn_perm(p1, p0, 0x05040100u);
    lw = __builtin_amdgcn_perm(p1, p0, 0x07060302u);
}
union S8U { short8 s8; unsigned u[4]; };
static __device__ __forceinline__ void build8v(u32x4 a, u32x4 b, short8& hi, short8& lo) {
    S8U H, L;
    unpack2w(a[0], a[1], H.u[0], L.u[0]);
    unpack2w(a[2], a[3], H.u[1], L.u[1]);
    unpack2w(b[0], b[1], H.u[2], L.u[2]);
    unpack2w(b[2], b[3], H.u[3], L.u[3]);
    hi = H.s8; lo = L.s8;
}
static __device__ __forceinline__ void split8v(f32x4 u, f32x4 v, short8& hi, short8& lo) {
#pragma unroll
    for (int j = 0; j < 4; ++j) { short h = f2bf(u[j]); hi[j] = h; lo[j] = f2bf(u[j] - bf2f(h)); }
#pragma unroll
    for (int j = 0; j < 4; ++j) { short h = f2bf(v[j]); hi[4+j] = h; lo[4+j] = f2bf(v[j] - bf2f(h)); }
}

// ---------------- Phase 1: xp(t) = input[t] @ Wx + bias -> out[t+1] --------
// Tile: 1 timestep (64 batch rows) x 64 cols; 16384 blocks of 256 threads.
// A (input) and W staged per-K-quarter in XOR-swizzled packed-u32 LDS;
// 3-chain bf16 hi/lo MFMA (identical numerics to the scan).
__global__ __launch_bounds__(256, 2) void rnn_xproj(
    const float* __restrict__ input, const float* __restrict__ weight,
    const float* __restrict__ bias, float* __restrict__ out)
{
    __shared__ unsigned alds[64 * 128];   // [row][k] packed, swizzled (32KB)
    __shared__ unsigned wlds[64 * 128];   // [col][k] packed, swizzled (32KB)
    const int tid = threadIdx.x, lane = tid & 63, wv = tid >> 6;
    const int t = blockIdx.x >> 3, ct = blockIdx.x & 7;
    const int r16 = lane & 15, kg = lane >> 4, koff = kg * 8;
    const int colt = wv * 16 + r16;       // col within the 64-tile
    const int gcol = ct * 64 + colt;
    const float bv = bias[gcol];

    f32x4 acc[4][3];
#pragma unroll
    for (int mt = 0; mt < 4; ++mt) {
        acc[mt][0] = (f32x4){bv, bv, bv, bv};
        acc[mt][1] = (f32x4){0, 0, 0, 0};
        acc[mt][2] = (f32x4){0, 0, 0, 0};
    }

    for (int kq = 0; kq < 4; ++kq) {
        __syncthreads();   // protect LDS reuse across quarters
        // stage A: 64 rows x 128 k, coalesced f32x4, split+pack, swizzled
        for (int f = tid; f < 64 * 32; f += 256) {
            const int row = f >> 5, sg = f & 31;
            f32x4 v = *(const f32x4*)(input + (size_t)t * SLICE_T + row * HDIM + kq * 128 + sg * 4);
            const unsigned idx = ((unsigned)(row * 128 + sg * 4)) ^ (((unsigned)(row & 7)) << 2);
            u32x4 pk = {packsplit(v[0]), packsplit(v[1]), packsplit(v[2]), packsplit(v[3])};
            *(u32x4*)(&alds[idx]) = pk;
        }
        // stage W transposed: [col][k] packed, swizzled
        for (int f = tid; f < 128 * 16; f += 256) {
            const int k = f >> 4, cs = f & 15;
            f32x4 v = *(const f32x4*)(weight + (size_t)(kq * 128 + k) * HDIM + ct * 64 + cs * 4);
#pragma unroll
            for (int j = 0; j < 4; ++j) {
                const int c = cs * 4 + j;
                wlds[((unsigned)(c * 128 + k)) ^ (((unsigned)(c & 7)) << 2)] = packsplit(v[j]);
            }
        }
        __syncthreads();
#pragma unroll
        for (int c2 = 0; c2 < 4; ++c2) {
            const int kp = c2 * 32 + koff;
            const unsigned bi = (unsigned)(colt * 128 + kp), bx = ((unsigned)(colt & 7)) << 2;
            u32x4 qb0 = *(const u32x4*)&wlds[bi ^ bx];
            u32x4 qb1 = *(const u32x4*)&wlds[(bi + 4) ^ bx];
            short8 bhi, blo; build8v(qb0, qb1, bhi, blo);
#pragma unroll
            for (int mt = 0; mt < 4; ++mt) {
                const int row = mt * 16 + r16;
                const unsigned ai = (unsigned)(row * 128 + kp), ax = ((unsigned)(row & 7)) << 2;
                u32x4 qa0 = *(const u32x4*)&alds[ai ^ ax];
                u32x4 qa1 = *(const u32x4*)&alds[(ai + 4) ^ ax];
                short8 ahi, alo; build8v(qa0, qa1, ahi, alo);
                acc[mt][0] = MFMA16(ahi, bhi, acc[mt][0], 0, 0, 0);
                acc[mt][1] = MFMA16(alo, bhi, acc[mt][1], 0, 0, 0);
                acc[mt][2] = MFMA16(ahi, blo, acc[mt][2], 0, 0, 0);
            }
        }
    }
    float* ob = out + (size_t)(t + 1) * SLICE_T;
#pragma unroll
    for (int mt = 0; mt < 4; ++mt)
#pragma unroll
        for (int r = 0; r < 4; ++r)
            ob[(mt * 16 + kg * 4 + r) * HDIM + gcol] =
                acc[mt][0][r] + acc[mt][1][r] + acc[mt][2][r];
}

// ---------------- Phase 2: persistent scan h_{t+1} = tanh(xp(t) + h_t@Wh) --
// 128 WGs = 8 groups x 16 slices (32 cols), 2 waves each, all co-resident.
// Wh lives in LDS as packed-u32 B-fragments (64KB) -> no VGPR spill.
// h exchanged via RMW swaps (coherence-point class, proven R5) in a 2-slot
// ring; per-(g,s) private canary lines (swap t+1) give the ready signal.
__global__ __launch_bounds__(128, 1) void rnn_scan(
    const float* __restrict__ weight, const float* __restrict__ init_h,
    float* __restrict__ out, unsigned char* __restrict__ ws)
{
    __shared__ u32x4 whfA[16][2][64];   // [kblock][wave][lane] first 16B (32KB)
    __shared__ u32x4 whfB[16][2][64];   // second 16B (32KB)
    unsigned* canary = (unsigned*)(ws + CAN_OFF);
    unsigned* ring   = (unsigned*)(ws + RING_OFF);

    const int tid = threadIdx.x, lane = tid & 63, wv = tid >> 6;
    const int g = blockIdx.x & 7, s = blockIdx.x >> 3;
    const int r16 = lane & 15, kg = lane >> 4, koff = kg * 8;
    const int gcol = s * 32 + wv * 16 + r16;
    const int brow = g * 8 + (r16 & 7);

    // one-time: Wh column-slice B-fragments into LDS (own-lane writes)
#pragma unroll
    for (int c = 0; c < 16; ++c) {
        unsigned p[8];
#pragma unroll
        for (int j = 0; j < 8; ++j)
            p[j] = packsplit(weight[(size_t)(HDIM + c * 32 + koff + j) * HDIM + gcol]);
        whfA[c][wv][lane] = (u32x4){p[0], p[1], p[2], p[3]};
        whfB[c][wv][lane] = (u32x4){p[4], p[5], p[6], p[7]};
    }
    // out[0] = broadcast init_hidden (this WG's tile)
    for (int f = tid; f < 8 * 32; f += 128) {
        const int rr = f >> 5, cc = f & 31;
        out[(size_t)(g * 8 + rr) * HDIM + s * 32 + cc] = init_h[s * 32 + cc];
    }
    __syncthreads();

    for (int t = 0; t < T_STEPS; ++t) {
        const unsigned tt = (unsigned)t;
        const bool has_next = (t + 1 < T_STEPS);

        // xp prefetch from out[t+1] (phase-1 data; only this WG overwrites it,
        // later in this step, ordered by the hn->xp data dependency)
        const float* xpp = out + (size_t)(t + 1) * SLICE_T
                               + (size_t)(g * 8 + (kg & 1) * 4) * HDIM + gcol;
        const float xp0 = xpp[0 * HDIM], xp1 = xpp[1 * HDIM];
        const float xp2 = xpp[2 * HDIM], xp3 = xpp[3 * HDIM];

        // wait: 16 lanes poll the group's 16 canary lines (bounded)
        int to = 0;
        if (t > 0) {
            if (wv == 0) {
                unsigned it = 0;
                for (;;) {
                    unsigned cv = 0xffffffffu;
                    if (lane < NSLICE) cv = ALOAD(&canary[(g * NSLICE + lane) * 32]);
                    if (__all((int)(cv >= tt))) break;
                    if (++it > SPIN_CAP) { to = 1; break; }
                }
            }
            if (__syncthreads_count(to)) return;   // hang-proof abort
        } else {
            __syncthreads();
        }

        // h_t @ Wh : A-frags from ring (or init_h), B-frags from LDS
        f32x4 aA = {0, 0, 0, 0}, aB = {0, 0, 0, 0}, aC = {0, 0, 0, 0};
        if (t == 0) {
#pragma unroll
            for (int c = 0; c < 16; ++c) {
                f32x4 u = *(const f32x4*)(init_h + c * 32 + koff);
                f32x4 v = *(const f32x4*)(init_h + c * 32 + koff + 4);
                short8 ahi, alo; split8v(u, v, ahi, alo);
                short8 bhi, blo; build8v(whfA[c][wv][lane], whfB[c][wv][lane], bhi, blo);
                aA = MFMA16(ahi, bhi, aA, 0, 0, 0);
                aB = MFMA16(alo, bhi, aB, 0, 0, 0);
                aC = MFMA16(ahi, blo, aC, 0, 0, 0);
            }
        } else {
            const unsigned* rb = ring + (t & 1) * SLICE_T + brow * HDIM;
#pragma unroll
            for (int c = 0; c < 16; ++c) {
                const unsigned* p = rb + c * 32 + koff;
                unsigned long long q0 = ALOAD((const unsigned long long*)(p + 0));
                unsigned long long q1 = ALOAD((const unsigned long long*)(p + 2));
                unsigned long long q2 = ALOAD((const unsigned long long*)(p + 4));
                unsigned long long q3 = ALOAD((const unsigned long long*)(p + 6));
                S8U hh, hl;
                unpack2w((unsigned)q0, (unsigned)(q0 >> 32), hh.u[0], hl.u[0]);
                unpack2w((unsigned)q1, (unsigned)(q1 >> 32), hh.u[1], hl.u[1]);
                unpack2w((unsigned)q2, (unsigned)(q2 >> 32), hh.u[2], hl.u[2]);
                unpack2w((unsigned)q3, (unsigned)(q3 >> 32), hh.u[3], hl.u[3]);
                short8 bhi, blo; build8v(whfA[c][wv][lane], whfB[c][wv][lane], bhi, blo);
                aA = MFMA16(hh.s8, bhi, aA, 0, 0, 0);
                aB = MFMA16(hl.s8, bhi, aB, 0, 0, 0);
                aC = MFMA16(hh.s8, blo, aC, 0, 0, 0);
            }
        }

        const float hn0 = tanhf(aA[0] + aB[0] + aC[0] + xp0);
        const float hn1 = tanhf(aA[1] + aB[1] + aC[1] + xp1);
        const float hn2 = tanhf(aA[2] + aB[2] + aC[2] + xp2);
        const float hn3 = tanhf(aA[3] + aB[3] + aC[3] + xp3);

        // post h_{t+1}: RMW swaps (at coherence point)
        if (kg < 2 && has_next) {
            unsigned* wsl = ring + ((t + 1) & 1) * SLICE_T
                                 + (size_t)(g * 8 + kg * 4) * HDIM + gcol;
            ASWAP(&wsl[0 * HDIM], packsplit(hn0));
            ASWAP(&wsl[1 * HDIM], packsplit(hn1));
            ASWAP(&wsl[2 * HDIM], packsplit(hn2));
            ASWAP(&wsl[3 * HDIM], packsplit(hn3));
        }
        asm volatile("s_waitcnt vmcnt(0)" ::: "memory");   // drain swaps
        __syncthreads();
        if (tid == 0 && has_next)
            ASWAP(&canary[(g * NSLICE + s) * 32], tt + 1u);

        // off the inter-WG critical path: final f32 h to out[t+1]
        if (kg < 2) {
            float* op = out + (size_t)(t + 1) * SLICE_T
                            + (size_t)(g * 8 + kg * 4) * HDIM + gcol;
            __builtin_nontemporal_store(hn0, op + 0 * HDIM);
            __builtin_nontemporal_store(hn1, op + 1 * HDIM);
            __builtin_nontemporal_store(hn2, op + 2 * HDIM);
            __builtin_nontemporal_store(hn3, op + 3 * HDIM);
        }
    }
}

extern "C" void kernel_launch(void* const* d_in, const int* in_sizes, int n_in,
                              void* d_out, int out_size, void* d_ws, size_t ws_size,
                              hipStream_t stream) {
    const float* input  = (const float*)d_in[0];
    const float* weight = (const float*)d_in[1];
    const float* biasp  = (const float*)d_in[2];
    const float* inith  = (const float*)d_in[3];
    float* out = (float*)d_out;

    // re-zero canaries each call (graph-replay deterministic); ring is
    // canary-gated and fully rewritten before any read.
    hipMemsetAsync(d_ws, 0, RING_OFF, stream);

    rnn_xproj<<<dim3(T_STEPS * 8), dim3(256), 0, stream>>>(input, weight, biasp, out);
    rnn_scan<<<dim3(NGROUP * NSLICE), dim3(128), 0, stream>>>(
        weight, inith, out, (unsigned char*)d_ws);
}